// Round 1
// baseline (193.058 us; speedup 1.0000x reference)
//
#include <hip/hip_runtime.h>

// GateRecurrent2dnoind: left-to-right SPN scan over W with 3-point stencil along H.
// Shapes: [N=8, C=64, H=256, W=256] fp32.
//
// Decomposition: 1 block per (n,c) plane; thread i owns row i (H=256 = blockDim).
// W is processed in tiles of WT=16 columns staged through LDS (coalesced float4
// global loads/stores); the sequential scan exchanges h[i-1]/h[i+1] through a
// double-buffered LDS line with one barrier per step.

constexpr int Hh  = 256;
constexpr int Ww  = 256;
constexpr int WT  = 16;
constexpr int PAD = WT + 1;  // 17: odd stride -> conflict-free stride-PAD LDS reads

__global__ __launch_bounds__(256, 2)
void spn_scan_kernel(const float* __restrict__ X,
                     const float* __restrict__ G1,
                     const float* __restrict__ G2,
                     const float* __restrict__ G3,
                     float* __restrict__ O)
{
    __shared__ float xt [Hh * PAD];
    __shared__ float g1t[Hh * PAD];
    __shared__ float g2t[Hh * PAD];
    __shared__ float g3t[Hh * PAD];
    __shared__ float hbuf[2][Hh + 2];   // zero-padded at [0] and [Hh+1]

    const int t     = threadIdx.x;       // row index 0..255
    const int plane = blockIdx.x;        // n*C + c
    const int base  = plane * (Hh * Ww);

    if (t < 2) {                          // boundary zeros, written once
        hbuf[t][0]      = 0.0f;
        hbuf[t][Hh + 1] = 0.0f;
    }

    float h = 0.0f;                       // h_prev for this row (h0 = 0)

    // cooperative-load lane mapping: thread t covers (row = q*64 + t/4, cols lcol..lcol+3)
    const int lrow = t >> 2;
    const int lcol = (t & 3) << 2;

    for (int w0 = 0; w0 < Ww; w0 += WT) {
        __syncthreads();   // previous tile fully consumed (incl. output staging reads)

        // ---- stage 4 input tiles [256][16] into LDS, coalesced float4 ----
        #pragma unroll
        for (int q = 0; q < 4; ++q) {
            const int row = q * 64 + lrow;
            const int g   = base + row * Ww + w0 + lcol;
            const int l   = row * PAD + lcol;
            const float4 vx = *reinterpret_cast<const float4*>(X  + g);
            const float4 v1 = *reinterpret_cast<const float4*>(G1 + g);
            const float4 v2 = *reinterpret_cast<const float4*>(G2 + g);
            const float4 v3 = *reinterpret_cast<const float4*>(G3 + g);
            xt [l+0]=vx.x; xt [l+1]=vx.y; xt [l+2]=vx.z; xt [l+3]=vx.w;
            g1t[l+0]=v1.x; g1t[l+1]=v1.y; g1t[l+2]=v1.z; g1t[l+3]=v1.w;
            g2t[l+0]=v2.x; g2t[l+1]=v2.y; g2t[l+2]=v2.z; g2t[l+3]=v2.w;
            g3t[l+0]=v3.x; g3t[l+1]=v3.y; g3t[l+2]=v3.z; g3t[l+3]=v3.w;
        }
        __syncthreads();

        // ---- sequential scan over the 16 columns of this tile ----
        #pragma unroll
        for (int ww = 0; ww < WT; ++ww) {
            float* hb = hbuf[ww & 1];
            hb[t + 1] = h;                // publish h_prev for neighbors
            __syncthreads();
            const float hu = hb[t];       // h_prev[i-1] (0 at i=0)
            const float hd = hb[t + 2];   // h_prev[i+1] (0 at i=255)
            const int   l  = t * PAD + ww;
            const float x  = xt [l];
            const float g1 = g1t[l];
            const float g2 = g2t[l];
            const float g3 = g3t[l];
            const float a  = 1.0f - g1 - g2 - g3;
            h = fmaf(g3, hd, fmaf(g2, h, fmaf(g1, hu, x * a)));
            xt[l] = h;                    // stash output in-place (row t is private here)
        }
        __syncthreads();

        // ---- coalesced float4 store of the tile's outputs ----
        #pragma unroll
        for (int q = 0; q < 4; ++q) {
            const int row = q * 64 + lrow;
            const int l   = row * PAD + lcol;
            const float4 v = make_float4(xt[l+0], xt[l+1], xt[l+2], xt[l+3]);
            const int g   = base + row * Ww + w0 + lcol;
            *reinterpret_cast<float4*>(O + g) = v;
        }
        // loop-top barrier protects xt reuse before the next tile load
    }
}

extern "C" void kernel_launch(void* const* d_in, const int* in_sizes, int n_in,
                              void* d_out, int out_size, void* d_ws, size_t ws_size,
                              hipStream_t stream) {
    const float* X  = (const float*)d_in[0];
    const float* G1 = (const float*)d_in[1];
    const float* G2 = (const float*)d_in[2];
    const float* G3 = (const float*)d_in[3];
    float* O = (float*)d_out;

    const int planes = 8 * 64;  // N*C
    spn_scan_kernel<<<dim3(planes), dim3(256), 0, stream>>>(X, G1, G2, G3, O);
}